// Round 5
// baseline (313.003 us; speedup 1.0000x reference)
//
#include <hip/hip_runtime.h>
#include <hip/hip_bf16.h>

#define HDIM 128

typedef __attribute__((ext_vector_type(8))) short bf16x8;   // 8 bf16 in 4 VGPRs
typedef __attribute__((ext_vector_type(4))) float f32x4;

__device__ inline unsigned short f2bf(float f) {
    return __builtin_bit_cast(unsigned short, __float2bfloat16(f));
}

// ---------------------------------------------------------------------------
// fused: zero deg+cursor (2N ints) and convert 3 W matrices to bf16 (49152 el)
__global__ void init_kernel(int* __restrict__ p, int n2,
                            const float* __restrict__ Wq, const float* __restrict__ Wk,
                            const float* __restrict__ Wv, unsigned short* __restrict__ Wb) {
    int i = blockIdx.x * 256 + threadIdx.x;
    if (i < n2) p[i] = 0;
    if (i < 3 * HDIM * HDIM) {
        int m = i >> 14, j = i & 16383;
        const float* W = (m == 0) ? Wq : (m == 1) ? Wk : Wv;
        Wb[i] = f2bf(W[j]);
    }
}

// ---------------------------------------------------------------------------
// MFMA projection. gridDim = (ceil(N/64), 3); 256 thr = 4 waves; wave = 16 nodes.
// No LDS, no barriers. A = x rows (fp32->bf16 in-reg), B = Wb rows (bf16).
// Output: planar bf16 [N][128] (Qb / Kb / Vb per blockIdx.y). Planar 2-byte
// stores L2-merge into full lines (round-4 evidence: Qb merged, interleaved
// KV did not -> 1.8x write amp).
__global__ __launch_bounds__(256, 4)
void proj_mfma(const float* __restrict__ qin, const float* __restrict__ kin,
               const float* __restrict__ vin, const unsigned short* __restrict__ Wb,
               const float* __restrict__ bq, const float* __restrict__ bk,
               const float* __restrict__ bv,
               unsigned short* __restrict__ Qb, unsigned short* __restrict__ Kb,
               unsigned short* __restrict__ Vb, int n)
{
    const int lane = threadIdx.x & 63;
    const int wv   = threadIdx.x >> 6;
    const int m    = blockIdx.y;
    const long node0 = (long)blockIdx.x * 64 + wv * 16;
    if (node0 >= n) return;

    const float* x = (m == 0) ? qin : (m == 1) ? kin : vin;
    const short* W = (const short*)(Wb + (size_t)m * HDIM * HDIM);
    const float* b = (m == 0) ? bq  : (m == 1) ? bk  : bv;
    unsigned short* O = (m == 0) ? Qb : (m == 1) ? Kb : Vb;

    const int row  = lane & 15;          // A: node row; B/D: out col
    const int quad = lane >> 4;

    // A fragments: 4 k-steps, 8 contiguous fp32 -> bf16x8 per lane
    bf16x8 af[4];
    const float* xrow = x + (size_t)(node0 + row) * HDIM + quad * 8;
    const bool rv = (node0 + row) < n;
    #pragma unroll
    for (int ks = 0; ks < 4; ++ks) {
        float4 lo = make_float4(0.f, 0.f, 0.f, 0.f);
        float4 hi = lo;
        if (rv) {
            lo = *(const float4*)(xrow + ks * 32);
            hi = *(const float4*)(xrow + ks * 32 + 4);
        }
        bf16x8 t;
        t[0] = (short)f2bf(lo.x); t[1] = (short)f2bf(lo.y);
        t[2] = (short)f2bf(lo.z); t[3] = (short)f2bf(lo.w);
        t[4] = (short)f2bf(hi.x); t[5] = (short)f2bf(hi.y);
        t[6] = (short)f2bf(hi.z); t[7] = (short)f2bf(hi.w);
        af[ks] = t;
    }

    #pragma unroll
    for (int nt = 0; nt < 8; ++nt) {
        f32x4 acc = {0.f, 0.f, 0.f, 0.f};
        // B frags: row (nt*16+row) of W, k = ks*32 + quad*8 .. +7 (contiguous bf16)
        const bf16x8* wr = (const bf16x8*)(W + (size_t)(nt * 16 + row) * HDIM + quad * 8);
        acc = __builtin_amdgcn_mfma_f32_16x16x32_bf16(af[0], wr[0],  acc, 0, 0, 0);
        acc = __builtin_amdgcn_mfma_f32_16x16x32_bf16(af[1], wr[4],  acc, 0, 0, 0);
        acc = __builtin_amdgcn_mfma_f32_16x16x32_bf16(af[2], wr[8],  acc, 0, 0, 0);
        acc = __builtin_amdgcn_mfma_f32_16x16x32_bf16(af[3], wr[12], acc, 0, 0, 0);

        const int c = nt * 16 + row;                 // output column
        const float bias = b[c];
        #pragma unroll
        for (int r = 0; r < 4; ++r) {
            long node = node0 + quad * 4 + r;        // D row = node within tile
            if (node < n) O[(size_t)node * HDIM + c] = f2bf(acc[r] + bias);
        }
    }
}

// ---------------------------------------------------------------------------
__global__ void deg_kernel(const int* __restrict__ qidx, int* __restrict__ deg, int E) {
    int e = blockIdx.x * blockDim.x + threadIdx.x;
    if (e < E) atomicAdd(&deg[qidx[e]], 1);
}

// multi-block exclusive scan: phase 1 — per-block scan + block totals
__global__ void scan_block(const int* __restrict__ deg, int* __restrict__ offs,
                           int* __restrict__ bsum, int n) {
    __shared__ int ws[17];
    const int tid = threadIdx.x;              // 1024
    const int lane = tid & 63, wv = tid >> 6;
    int i = blockIdx.x * 1024 + tid;
    int v = (i < n) ? deg[i] : 0;
    int sc = v;
    #pragma unroll
    for (int d = 1; d < 64; d <<= 1) {
        int t = __shfl_up(sc, d, 64);
        if (lane >= d) sc += t;
    }
    if (lane == 63) ws[wv] = sc;
    __syncthreads();
    if (tid == 0) {
        int base = 0;
        #pragma unroll
        for (int w = 0; w < 16; ++w) { int t = ws[w]; ws[w] = base; base += t; }
        ws[16] = base;
    }
    __syncthreads();
    if (i < n) offs[i] = ws[wv] + (sc - v);
    if (tid == 0) bsum[blockIdx.x] = ws[16];
}

// phase 2 — exclusive scan of block totals (nb <= 64 fast path)
__global__ void scan_tops(int* __restrict__ bsum, int nb) {
    if (nb <= 64) {
        int lane = threadIdx.x;
        int v = (lane < nb) ? bsum[lane] : 0;
        int sc = v;
        #pragma unroll
        for (int d = 1; d < 64; d <<= 1) {
            int t = __shfl_up(sc, d, 64);
            if (lane >= d) sc += t;
        }
        if (lane < nb) bsum[lane] = sc - v;
    } else if (threadIdx.x == 0) {
        int base = 0;
        for (int i = 0; i < nb; ++i) { int t = bsum[i]; bsum[i] = base; base += t; }
    }
}

// phase 3 — add block bases; also write offs[n] = E
__global__ void scan_add(const int* __restrict__ bsum, int* __restrict__ offs,
                         int n, int E) {
    int i = blockIdx.x * blockDim.x + threadIdx.x;
    if (i < n) offs[i] += bsum[i >> 10];
    if (i == 0) offs[n] = E;
}

// scatter SRC NODE IDS into CSR buckets
__global__ void fill_kernel(const int* __restrict__ qidx, const int* __restrict__ kidx,
                            const int* __restrict__ offs, int* __restrict__ cursor,
                            int* __restrict__ srcl, int E) {
    int e = blockIdx.x * blockDim.x + threadIdx.x;
    if (e < E) {
        int d = qidx[e];
        int pos = offs[d] + atomicAdd(&cursor[d], 1);
        srcl[pos] = kidx[e];
    }
}

// ---------------------------------------------------------------------------
// Aggregation: one wave per destination node. Lane l owns dim pair (2l,2l+1);
// head a = l>>3; D=16 dot reduced via 3 shfl_xor within 8 lanes.
// Q/K/V planar bf16: per edge, one uint (4B) load from Ku + one from Vu.
__global__ void agg_kernel(const unsigned* __restrict__ Qu, const unsigned* __restrict__ Ku,
                           const unsigned* __restrict__ Vu,
                           const int* __restrict__ offs, const int* __restrict__ srcl,
                           float* __restrict__ out, int n)
{
    const int lane = threadIdx.x & 63;
    const int wid  = threadIdx.x >> 6;
    const int node = blockIdx.x * 4 + wid;
    if (node >= n) return;

    unsigned qu = Qu[(size_t)node * 64 + lane];
    const float qx = __uint_as_float(qu << 16);
    const float qy = __uint_as_float(qu & 0xffff0000u);

    float acc0 = 0.f, acc1 = 0.f, dsum = 0.f;
    const int beg = offs[node], end = offs[node + 1];

#define EDGE_STEP(ku, vu)                                                      \
    {                                                                          \
        float kx = __uint_as_float((ku) << 16);                                \
        float ky = __uint_as_float((ku) & 0xffff0000u);                        \
        float vx = __uint_as_float((vu) << 16);                                \
        float vy = __uint_as_float((vu) & 0xffff0000u);                        \
        float part = qx * kx + qy * ky;                                        \
        part += __shfl_xor(part, 1, 64);                                       \
        part += __shfl_xor(part, 2, 64);                                       \
        part += __shfl_xor(part, 4, 64);                                       \
        float w = __expf(part * 0.25f);                                        \
        dsum += w; acc0 += w * vx; acc1 += w * vy;                             \
    }

    for (int base = beg; base < end; base += 64) {
        int cnt = min(64, end - base);
        int my = (base + lane < end) ? srcl[base + lane] : 0;
        int j = 0;
        for (; j + 4 <= cnt; j += 4) {
            int s0 = __shfl(my, j,     64);
            int s1 = __shfl(my, j + 1, 64);
            int s2 = __shfl(my, j + 2, 64);
            int s3 = __shfl(my, j + 3, 64);
            unsigned k0 = Ku[(size_t)s0 * 64 + lane];
            unsigned v0 = Vu[(size_t)s0 * 64 + lane];
            unsigned k1 = Ku[(size_t)s1 * 64 + lane];
            unsigned v1 = Vu[(size_t)s1 * 64 + lane];
            unsigned k2 = Ku[(size_t)s2 * 64 + lane];
            unsigned v2 = Vu[(size_t)s2 * 64 + lane];
            unsigned k3 = Ku[(size_t)s3 * 64 + lane];
            unsigned v3 = Vu[(size_t)s3 * 64 + lane];
            EDGE_STEP(k0, v0); EDGE_STEP(k1, v1);
            EDGE_STEP(k2, v2); EDGE_STEP(k3, v3);
        }
        for (; j < cnt; ++j) {
            int s = __shfl(my, j, 64);
            unsigned kk = Ku[(size_t)s * 64 + lane];
            unsigned vv = Vu[(size_t)s * 64 + lane];
            EDGE_STEP(kk, vv);
        }
    }
#undef EDGE_STEP

    float inv = 1.f / dsum;                   // deg>=1 (identity edges present)
    *(float2*)&out[(size_t)node * HDIM + lane * 2] = make_float2(acc0 * inv, acc1 * inv);
}

// ---------------------------------------------------------------------------
extern "C" void kernel_launch(void* const* d_in, const int* in_sizes, int n_in,
                              void* d_out, int out_size, void* d_ws, size_t ws_size,
                              hipStream_t stream) {
    const float* q  = (const float*)d_in[0];
    const float* k  = (const float*)d_in[1];
    const float* v  = (const float*)d_in[2];
    const float* Wq = (const float*)d_in[3];
    const float* bq = (const float*)d_in[4];
    const float* Wk = (const float*)d_in[5];
    const float* bk = (const float*)d_in[6];
    const float* Wv = (const float*)d_in[7];
    const float* bv = (const float*)d_in[8];
    const int* qidx = (const int*)d_in[9];
    const int* kidx = (const int*)d_in[10];
    float* out = (float*)d_out;

    const int N = in_sizes[0] / HDIM;
    const int E = in_sizes[9];

    char* p = (char*)d_ws;
    unsigned short* Qb = (unsigned short*)p; p += (size_t)N * HDIM * sizeof(unsigned short);
    unsigned short* Kb = (unsigned short*)p; p += (size_t)N * HDIM * sizeof(unsigned short);
    unsigned short* Vb = (unsigned short*)p; p += (size_t)N * HDIM * sizeof(unsigned short);
    unsigned short* Wb = (unsigned short*)p; p += (size_t)3 * HDIM * HDIM * sizeof(unsigned short);
    int* deg    = (int*)p; p += (size_t)N * sizeof(int);
    int* cursor = (int*)p; p += (size_t)N * sizeof(int);   // contiguous with deg
    int* offs   = (int*)p; p += (size_t)(N + 1) * sizeof(int);
    int* bsum   = (int*)p; p += 64 * sizeof(int);
    int* srcl   = (int*)p; p += (size_t)E * sizeof(int);

    const int nb = (N + 1023) / 1024;
    const int initn = (2 * N > 3 * HDIM * HDIM) ? 2 * N : 3 * HDIM * HDIM;

    init_kernel<<<(initn + 255) / 256, 256, 0, stream>>>(deg, 2 * N, Wq, Wk, Wv, Wb);
    {
        dim3 grid((N + 63) / 64, 3);
        proj_mfma<<<grid, 256, 0, stream>>>(q, k, v, Wb, bq, bk, bv, Qb, Kb, Vb, N);
    }
    deg_kernel<<<(E + 255) / 256, 256, 0, stream>>>(qidx, deg, E);
    scan_block<<<nb, 1024, 0, stream>>>(deg, offs, bsum, N);
    scan_tops<<<1, 64, 0, stream>>>(bsum, nb);
    scan_add<<<(N + 1023) / 1024, 1024, 0, stream>>>(bsum, offs, N, E);
    fill_kernel<<<(E + 255) / 256, 256, 0, stream>>>(qidx, kidx, offs, cursor, srcl, E);
    agg_kernel<<<(N + 3) / 4, 256, 0, stream>>>((const unsigned*)Qb, (const unsigned*)Kb,
                                                (const unsigned*)Vb, offs, srcl, out, N);
}

// Round 6
// 281.869 us; speedup vs baseline: 1.1105x; 1.1105x over previous
//
#include <hip/hip_runtime.h>
#include <hip/hip_bf16.h>

#define HDIM 128
#define LDS_STRIDE 136   // 128 + 8 ushorts pad: 272B rows -> 16B aligned, bank-floor

typedef __attribute__((ext_vector_type(8))) short bf16x8;   // 8 bf16 in 4 VGPRs
typedef __attribute__((ext_vector_type(4))) float f32x4;

__device__ inline unsigned short f2bf(float f) {
    return __builtin_bit_cast(unsigned short, __float2bfloat16(f));
}

// ---------------------------------------------------------------------------
// fused init: zero deg+cursor (2N ints) and build Wopt — W rearranged into
// MFMA B-fragment order: chunk index (m, nt, ks, lane) -> 8 ushorts =
// W_m[row = nt*16+(lane&15)][col = ks*32+(lane>>4)*8 .. +7]; proj's B loads
// become lane-contiguous 1KB/instruction.
__global__ void init_kernel(int* __restrict__ p, int n2,
                            const float* __restrict__ Wq, const float* __restrict__ Wk,
                            const float* __restrict__ Wv, unsigned short* __restrict__ Wopt) {
    int i = blockIdx.x * 256 + threadIdx.x;
    if (i < n2) p[i] = 0;
    if (i < 3 * HDIM * HDIM) {
        int j  = i & 7;
        int l  = (i >> 3) & 63;
        int ks = (i >> 9) & 3;
        int nt = (i >> 11) & 7;
        int m  = i >> 14;
        const float* W = (m == 0) ? Wq : (m == 1) ? Wk : Wv;
        int row = nt * 16 + (l & 15);
        int col = ks * 32 + ((l >> 4) << 3) + j;
        Wopt[i] = f2bf(W[row * HDIM + col]);
    }
}

// ---------------------------------------------------------------------------
// MFMA projection with LDS staging. grid = (ceil(N/64), 3); 256 thr = 4 waves.
__global__ void proj_mfma(const float* __restrict__ qin, const float* __restrict__ kin,
                          const float* __restrict__ vin, const unsigned short* __restrict__ Wopt,
                          const float* __restrict__ bq, const float* __restrict__ bk,
                          const float* __restrict__ bv,
                          unsigned short* __restrict__ Qb, unsigned short* __restrict__ Kb,
                          unsigned short* __restrict__ Vb, int n)
{
    __shared__ unsigned short tile[64 * LDS_STRIDE];   // 17408 B

    const int tid  = threadIdx.x;
    const int lane = tid & 63;
    const int wv   = tid >> 6;
    const int m    = blockIdx.y;
    const long node0 = (long)blockIdx.x * 64;

    const float* x = (m == 0) ? qin : (m == 1) ? kin : vin;
    const float* b = (m == 0) ? bq  : (m == 1) ? bk  : bv;
    unsigned short* O = (m == 0) ? Qb : (m == 1) ? Kb : Vb;
    const unsigned short* Wm = Wopt + (size_t)m * HDIM * HDIM;

    // ---- Phase 1: stage x tile (64x128 fp32, contiguous) as bf16 in LDS ----
    #pragma unroll
    for (int it = 0; it < 8; ++it) {
        int f   = it * 256 + tid;          // float4 slot 0..2047
        int row = f >> 5;                  // 32 float4 per row
        int c4  = f & 31;
        long node = node0 + row;
        float4 val = make_float4(0.f, 0.f, 0.f, 0.f);
        if (node < n) val = ((const float4*)(x + node * HDIM))[c4];
        ushort4 h;
        h.x = f2bf(val.x); h.y = f2bf(val.y); h.z = f2bf(val.z); h.w = f2bf(val.w);
        *(ushort4*)&tile[row * LDS_STRIDE + c4 * 4] = h;   // ds_write_b64
    }
    __syncthreads();

    // ---- Phase 2: MFMA ----
    const int r15  = lane & 15;
    const int quad = lane >> 4;

    bf16x8 af[4];
    #pragma unroll
    for (int ks = 0; ks < 4; ++ks)
        af[ks] = *(const bf16x8*)&tile[(wv * 16 + r15) * LDS_STRIDE + quad * 8 + ks * 32];

    f32x4 acc[8];
    #pragma unroll
    for (int nt = 0; nt < 8; ++nt) {
        acc[nt] = (f32x4){0.f, 0.f, 0.f, 0.f};
        #pragma unroll
        for (int ks = 0; ks < 4; ++ks) {
            const bf16x8 wfrag =
                *(const bf16x8*)(Wm + ((size_t)((nt * 4 + ks) * 64) + lane) * 8);
            acc[nt] = __builtin_amdgcn_mfma_f32_16x16x32_bf16(af[ks], wfrag, acc[nt], 0, 0, 0);
        }
    }
    __syncthreads();                       // tile free for D reuse

    // ---- Phase 3: D -> LDS (bias added) -> coalesced dwordx4 stores ----
    #pragma unroll
    for (int nt = 0; nt < 8; ++nt) {
        const int c = nt * 16 + r15;
        const float bias = b[c];
        #pragma unroll
        for (int r = 0; r < 4; ++r)
            tile[(wv * 16 + quad * 4 + r) * LDS_STRIDE + c] = f2bf(acc[nt][r] + bias);
    }
    __syncthreads();

    #pragma unroll
    for (int it = 0; it < 4; ++it) {
        int g   = it * 256 + tid;          // ushort8 chunk 0..1023
        int row = g >> 4;                  // 16 chunks per row
        int col = (g & 15) * 8;
        long node = node0 + row;
        if (node < n) {
            ushort4 lo = *(const ushort4*)&tile[row * LDS_STRIDE + col];
            ushort4 hi = *(const ushort4*)&tile[row * LDS_STRIDE + col + 4];
            uint4 out4;
            out4.x = (unsigned)lo.x | ((unsigned)lo.y << 16);
            out4.y = (unsigned)lo.z | ((unsigned)lo.w << 16);
            out4.z = (unsigned)hi.x | ((unsigned)hi.y << 16);
            out4.w = (unsigned)hi.z | ((unsigned)hi.w << 16);
            *(uint4*)&O[node * HDIM + col] = out4;
        }
    }
}

// ---------------------------------------------------------------------------
__global__ void deg_kernel(const int* __restrict__ qidx, int* __restrict__ deg, int E) {
    int e = blockIdx.x * blockDim.x + threadIdx.x;
    if (e < E) atomicAdd(&deg[qidx[e]], 1);
}

// multi-block exclusive scan: phase 1 — per-block scan + block totals
__global__ void scan_block(const int* __restrict__ deg, int* __restrict__ offs,
                           int* __restrict__ bsum, int n) {
    __shared__ int ws[17];
    const int tid = threadIdx.x;              // 1024
    const int lane = tid & 63, wv = tid >> 6;
    int i = blockIdx.x * 1024 + tid;
    int v = (i < n) ? deg[i] : 0;
    int sc = v;
    #pragma unroll
    for (int d = 1; d < 64; d <<= 1) {
        int t = __shfl_up(sc, d, 64);
        if (lane >= d) sc += t;
    }
    if (lane == 63) ws[wv] = sc;
    __syncthreads();
    if (tid == 0) {
        int base = 0;
        #pragma unroll
        for (int w = 0; w < 16; ++w) { int t = ws[w]; ws[w] = base; base += t; }
        ws[16] = base;
    }
    __syncthreads();
    if (i < n) offs[i] = ws[wv] + (sc - v);
    if (tid == 0) bsum[blockIdx.x] = ws[16];
}

// phase 2 — exclusive scan of block totals (nb <= 64 fast path)
__global__ void scan_tops(int* __restrict__ bsum, int nb) {
    if (nb <= 64) {
        int lane = threadIdx.x;
        int v = (lane < nb) ? bsum[lane] : 0;
        int sc = v;
        #pragma unroll
        for (int d = 1; d < 64; d <<= 1) {
            int t = __shfl_up(sc, d, 64);
            if (lane >= d) sc += t;
        }
        if (lane < nb) bsum[lane] = sc - v;
    } else if (threadIdx.x == 0) {
        int base = 0;
        for (int i = 0; i < nb; ++i) { int t = bsum[i]; bsum[i] = base; base += t; }
    }
}

// phase 3 — add block bases; also write offs[n] = E
__global__ void scan_add(const int* __restrict__ bsum, int* __restrict__ offs,
                         int n, int E) {
    int i = blockIdx.x * blockDim.x + threadIdx.x;
    if (i < n) offs[i] += bsum[i >> 10];
    if (i == 0) offs[n] = E;
}

// scatter SRC NODE IDS into CSR buckets
__global__ void fill_kernel(const int* __restrict__ qidx, const int* __restrict__ kidx,
                            const int* __restrict__ offs, int* __restrict__ cursor,
                            int* __restrict__ srcl, int E) {
    int e = blockIdx.x * blockDim.x + threadIdx.x;
    if (e < E) {
        int d = qidx[e];
        int pos = offs[d] + atomicAdd(&cursor[d], 1);
        srcl[pos] = kidx[e];
    }
}

// ---------------------------------------------------------------------------
// Aggregation: one wave per destination node. Lane l owns dim pair (2l,2l+1);
// head a = l>>3; D=16 dot reduced via 3 shfl_xor within 8 lanes.
__global__ void agg_kernel(const unsigned* __restrict__ Qu, const unsigned* __restrict__ Ku,
                           const unsigned* __restrict__ Vu,
                           const int* __restrict__ offs, const int* __restrict__ srcl,
                           float* __restrict__ out, int n)
{
    const int lane = threadIdx.x & 63;
    const int wid  = threadIdx.x >> 6;
    const int node = blockIdx.x * 4 + wid;
    if (node >= n) return;

    unsigned qu = Qu[(size_t)node * 64 + lane];
    const float qx = __uint_as_float(qu << 16);
    const float qy = __uint_as_float(qu & 0xffff0000u);

    float acc0 = 0.f, acc1 = 0.f, dsum = 0.f;
    const int beg = offs[node], end = offs[node + 1];

#define EDGE_STEP(ku, vu)                                                      \
    {                                                                          \
        float kx = __uint_as_float((ku) << 16);                                \
        float ky = __uint_as_float((ku) & 0xffff0000u);                        \
        float vx = __uint_as_float((vu) << 16);                                \
        float vy = __uint_as_float((vu) & 0xffff0000u);                        \
        float part = qx * kx + qy * ky;                                        \
        part += __shfl_xor(part, 1, 64);                                       \
        part += __shfl_xor(part, 2, 64);                                       \
        part += __shfl_xor(part, 4, 64);                                       \
        float w = __expf(part * 0.25f);                                        \
        dsum += w; acc0 += w * vx; acc1 += w * vy;                             \
    }

    for (int base = beg; base < end; base += 64) {
        int cnt = min(64, end - base);
        int my = (base + lane < end) ? srcl[base + lane] : 0;
        int j = 0;
        for (; j + 4 <= cnt; j += 4) {
            int s0 = __shfl(my, j,     64);
            int s1 = __shfl(my, j + 1, 64);
            int s2 = __shfl(my, j + 2, 64);
            int s3 = __shfl(my, j + 3, 64);
            unsigned k0 = Ku[(size_t)s0 * 64 + lane];
            unsigned v0 = Vu[(size_t)s0 * 64 + lane];
            unsigned k1 = Ku[(size_t)s1 * 64 + lane];
            unsigned v1 = Vu[(size_t)s1 * 64 + lane];
            unsigned k2 = Ku[(size_t)s2 * 64 + lane];
            unsigned v2 = Vu[(size_t)s2 * 64 + lane];
            unsigned k3 = Ku[(size_t)s3 * 64 + lane];
            unsigned v3 = Vu[(size_t)s3 * 64 + lane];
            EDGE_STEP(k0, v0); EDGE_STEP(k1, v1);
            EDGE_STEP(k2, v2); EDGE_STEP(k3, v3);
        }
        for (; j < cnt; ++j) {
            int s = __shfl(my, j, 64);
            unsigned kk = Ku[(size_t)s * 64 + lane];
            unsigned vv = Vu[(size_t)s * 64 + lane];
            EDGE_STEP(kk, vv);
        }
    }
#undef EDGE_STEP

    float inv = 1.f / dsum;                   // deg>=1 (identity edges present)
    *(float2*)&out[(size_t)node * HDIM + lane * 2] = make_float2(acc0 * inv, acc1 * inv);
}

// ---------------------------------------------------------------------------
extern "C" void kernel_launch(void* const* d_in, const int* in_sizes, int n_in,
                              void* d_out, int out_size, void* d_ws, size_t ws_size,
                              hipStream_t stream) {
    const float* q  = (const float*)d_in[0];
    const float* k  = (const float*)d_in[1];
    const float* v  = (const float*)d_in[2];
    const float* Wq = (const float*)d_in[3];
    const float* bq = (const float*)d_in[4];
    const float* Wk = (const float*)d_in[5];
    const float* bk = (const float*)d_in[6];
    const float* Wv = (const float*)d_in[7];
    const float* bv = (const float*)d_in[8];
    const int* qidx = (const int*)d_in[9];
    const int* kidx = (const int*)d_in[10];
    float* out = (float*)d_out;

    const int N = in_sizes[0] / HDIM;
    const int E = in_sizes[9];

    char* p = (char*)d_ws;
    unsigned short* Qb = (unsigned short*)p; p += (size_t)N * HDIM * sizeof(unsigned short);
    unsigned short* Kb = (unsigned short*)p; p += (size_t)N * HDIM * sizeof(unsigned short);
    unsigned short* Vb = (unsigned short*)p; p += (size_t)N * HDIM * sizeof(unsigned short);
    unsigned short* Wopt = (unsigned short*)p; p += (size_t)3 * HDIM * HDIM * sizeof(unsigned short);
    int* deg    = (int*)p; p += (size_t)N * sizeof(int);
    int* cursor = (int*)p; p += (size_t)N * sizeof(int);   // contiguous with deg
    int* offs   = (int*)p; p += (size_t)(N + 1) * sizeof(int);
    int* bsum   = (int*)p; p += 64 * sizeof(int);
    int* srcl   = (int*)p; p += (size_t)E * sizeof(int);

    const int nb = (N + 1023) / 1024;
    const int initn = (2 * N > 3 * HDIM * HDIM) ? 2 * N : 3 * HDIM * HDIM;

    init_kernel<<<(initn + 255) / 256, 256, 0, stream>>>(deg, 2 * N, Wq, Wk, Wv, Wopt);
    {
        dim3 grid((N + 63) / 64, 3);
        proj_mfma<<<grid, 256, 0, stream>>>(q, k, v, Wopt, bq, bk, bv, Qb, Kb, Vb, N);
    }
    deg_kernel<<<(E + 255) / 256, 256, 0, stream>>>(qidx, deg, E);
    scan_block<<<nb, 1024, 0, stream>>>(deg, offs, bsum, N);
    scan_tops<<<1, 64, 0, stream>>>(bsum, nb);
    scan_add<<<(N + 1023) / 1024, 1024, 0, stream>>>(bsum, offs, N, E);
    fill_kernel<<<(E + 255) / 256, 256, 0, stream>>>(qidx, kidx, offs, cursor, srcl, E);
    agg_kernel<<<(N + 3) / 4, 256, 0, stream>>>((const unsigned*)Qb, (const unsigned*)Kb,
                                                (const unsigned*)Vb, offs, srcl, out, N);
}

// Round 7
// 248.365 us; speedup vs baseline: 1.2603x; 1.1349x over previous
//
#include <hip/hip_runtime.h>
#include <hip/hip_bf16.h>

#define HDIM 128
#define LDS_STRIDE 136   // 128 + 8 ushorts pad: 272B rows -> 16B aligned, bank-floor

typedef __attribute__((ext_vector_type(8))) short bf16x8;   // 8 bf16 in 4 VGPRs
typedef __attribute__((ext_vector_type(4))) float f32x4;

__device__ inline unsigned short f2bf(float f) {
    return __builtin_bit_cast(unsigned short, __float2bfloat16(f));
}
__device__ inline float bflo(unsigned u) { return __uint_as_float(u << 16); }
__device__ inline float bfhi(unsigned u) { return __uint_as_float(u & 0xffff0000u); }

// ---------------------------------------------------------------------------
// init: zero deg (N ints) and build Wopt — W in MFMA B-fragment order:
// chunk (m, nt, ks, lane) -> 8 ushorts = W_m[nt*16+(lane&15)][ks*32+(lane>>4)*8..+7]
__global__ void init_kernel(int* __restrict__ deg, int n,
                            const float* __restrict__ Wq, const float* __restrict__ Wk,
                            const float* __restrict__ Wv, unsigned short* __restrict__ Wopt) {
    int i = blockIdx.x * 256 + threadIdx.x;
    if (i < n) deg[i] = 0;
    if (i < 3 * HDIM * HDIM) {
        int j  = i & 7;
        int l  = (i >> 3) & 63;
        int ks = (i >> 9) & 3;
        int nt = (i >> 11) & 7;
        int m  = i >> 14;
        const float* W = (m == 0) ? Wq : (m == 1) ? Wk : Wv;
        int row = nt * 16 + (l & 15);
        int col = ks * 32 + ((l >> 4) << 3) + j;
        Wopt[i] = f2bf(W[row * HDIM + col]);
    }
}

// ---------------------------------------------------------------------------
// Fused dispatch: blockIdx.y in {0,1,2} -> MFMA projection (Q/K/V);
// blockIdx.y==3 -> degree count with rank capture (overlaps with proj —
// independent data). rank[e] = old deg value = position within dest bucket.
__global__ void proj_deg(const float* __restrict__ qin, const float* __restrict__ kin,
                         const float* __restrict__ vin, const unsigned short* __restrict__ Wopt,
                         const float* __restrict__ bq, const float* __restrict__ bk,
                         const float* __restrict__ bv,
                         unsigned short* __restrict__ Qb, unsigned short* __restrict__ Kb,
                         unsigned short* __restrict__ Vb,
                         const int* __restrict__ qidx, int* __restrict__ deg,
                         int* __restrict__ rank, int E, int n, int nbx)
{
    __shared__ unsigned short tile[64 * LDS_STRIDE];   // 17408 B

    if (blockIdx.y == 3) {                  // degree-count slice
        int e = blockIdx.x * 256 + threadIdx.x;
        if (e < E) rank[e] = atomicAdd(&deg[qidx[e]], 1);
        return;
    }
    if (blockIdx.x >= (unsigned)nbx) return;

    const int tid  = threadIdx.x;
    const int lane = tid & 63;
    const int wv   = tid >> 6;
    const int m    = blockIdx.y;
    const long node0 = (long)blockIdx.x * 64;

    const float* x = (m == 0) ? qin : (m == 1) ? kin : vin;
    const float* b = (m == 0) ? bq  : (m == 1) ? bk  : bv;
    unsigned short* O = (m == 0) ? Qb : (m == 1) ? Kb : Vb;
    const unsigned short* Wm = Wopt + (size_t)m * HDIM * HDIM;

    // Phase 1: stage x tile (64x128 fp32, contiguous) as bf16 in LDS
    #pragma unroll
    for (int it = 0; it < 8; ++it) {
        int f   = it * 256 + tid;
        int row = f >> 5;
        int c4  = f & 31;
        long node = node0 + row;
        float4 val = make_float4(0.f, 0.f, 0.f, 0.f);
        if (node < n) val = ((const float4*)(x + node * HDIM))[c4];
        ushort4 h;
        h.x = f2bf(val.x); h.y = f2bf(val.y); h.z = f2bf(val.z); h.w = f2bf(val.w);
        *(ushort4*)&tile[row * LDS_STRIDE + c4 * 4] = h;
    }
    __syncthreads();

    // Phase 2: MFMA
    const int r15  = lane & 15;
    const int quad = lane >> 4;

    bf16x8 af[4];
    #pragma unroll
    for (int ks = 0; ks < 4; ++ks)
        af[ks] = *(const bf16x8*)&tile[(wv * 16 + r15) * LDS_STRIDE + quad * 8 + ks * 32];

    f32x4 acc[8];
    #pragma unroll
    for (int nt = 0; nt < 8; ++nt) {
        acc[nt] = (f32x4){0.f, 0.f, 0.f, 0.f};
        #pragma unroll
        for (int ks = 0; ks < 4; ++ks) {
            const bf16x8 wfrag =
                *(const bf16x8*)(Wm + ((size_t)((nt * 4 + ks) * 64) + lane) * 8);
            acc[nt] = __builtin_amdgcn_mfma_f32_16x16x32_bf16(af[ks], wfrag, acc[nt], 0, 0, 0);
        }
    }
    __syncthreads();                        // tile free for D reuse

    // Phase 3: D -> LDS (bias added) -> coalesced dwordx4 stores
    #pragma unroll
    for (int nt = 0; nt < 8; ++nt) {
        const int c = nt * 16 + r15;
        const float bias = b[c];
        #pragma unroll
        for (int r = 0; r < 4; ++r)
            tile[(wv * 16 + quad * 4 + r) * LDS_STRIDE + c] = f2bf(acc[nt][r] + bias);
    }
    __syncthreads();

    #pragma unroll
    for (int it = 0; it < 4; ++it) {
        int g   = it * 256 + tid;
        int row = g >> 4;
        int col = (g & 15) * 8;
        long node = node0 + row;
        if (node < n) {
            ushort4 lo = *(const ushort4*)&tile[row * LDS_STRIDE + col];
            ushort4 hi = *(const ushort4*)&tile[row * LDS_STRIDE + col + 4];
            uint4 out4;
            out4.x = (unsigned)lo.x | ((unsigned)lo.y << 16);
            out4.y = (unsigned)lo.z | ((unsigned)lo.w << 16);
            out4.z = (unsigned)hi.x | ((unsigned)hi.y << 16);
            out4.w = (unsigned)hi.z | ((unsigned)hi.w << 16);
            *(uint4*)&O[node * HDIM + col] = out4;
        }
    }
}

// ---------------------------------------------------------------------------
// scan phase 1 — per-block inclusive->exclusive scan + block totals
__global__ void scan_block(const int* __restrict__ deg, int* __restrict__ offs,
                           int* __restrict__ bsum, int n) {
    __shared__ int ws[17];
    const int tid = threadIdx.x;              // 1024
    const int lane = tid & 63, wv = tid >> 6;
    int i = blockIdx.x * 1024 + tid;
    int v = (i < n) ? deg[i] : 0;
    int sc = v;
    #pragma unroll
    for (int d = 1; d < 64; d <<= 1) {
        int t = __shfl_up(sc, d, 64);
        if (lane >= d) sc += t;
    }
    if (lane == 63) ws[wv] = sc;
    __syncthreads();
    if (tid == 0) {
        int base = 0;
        #pragma unroll
        for (int w = 0; w < 16; ++w) { int t = ws[w]; ws[w] = base; base += t; }
        ws[16] = base;
    }
    __syncthreads();
    if (i < n) offs[i] = ws[wv] + (sc - v);
    if (tid == 0) bsum[blockIdx.x] = ws[16];
}

// scan phase 2 — each block redundantly wave-scans bsum (nb<=64) and adds its base
__global__ void scan_addtops(const int* __restrict__ bsum, int* __restrict__ offs,
                             int n, int E, int nb) {
    __shared__ int s_base;
    const int tid = threadIdx.x;
    if (tid < 64) {
        int v = (tid < nb) ? bsum[tid] : 0;
        int sc = v;
        #pragma unroll
        for (int d = 1; d < 64; d <<= 1) {
            int t = __shfl_up(sc, d, 64);
            if (tid >= d) sc += t;
        }
        if (tid == blockIdx.x) s_base = sc - v;   // exclusive prefix of this block
    }
    __syncthreads();
    int i = blockIdx.x * 1024 + tid;
    if (i < n) offs[i] += s_base;
    if (blockIdx.x == 0 && tid == 0) offs[n] = E;
}

// scatter src node ids using precomputed ranks — no atomics
__global__ void fill_kernel(const int* __restrict__ qidx, const int* __restrict__ kidx,
                            const int* __restrict__ offs, const int* __restrict__ rank,
                            int* __restrict__ srcl, int E) {
    int e = blockIdx.x * blockDim.x + threadIdx.x;
    if (e < E) srcl[offs[qidx[e]] + rank[e]] = kidx[e];
}

// ---------------------------------------------------------------------------
// Aggregation: HALF-WAVE (32 lanes) per destination node. Lane l32 owns dims
// 4*l32..4*l32+3 (one uint2 = 4 bf16); head = l32>>2 -> D=16 dot reduced with
// 2 shfl_xor within 4 lanes. 256 thr = 8 nodes/block.
__global__ void agg_kernel(const uint2* __restrict__ Q2, const uint2* __restrict__ K2,
                           const uint2* __restrict__ V2,
                           const int* __restrict__ offs, const int* __restrict__ srcl,
                           float* __restrict__ out, int n)
{
    const int tid  = threadIdx.x;
    const int l32  = tid & 31;
    const int node = blockIdx.x * 8 + (tid >> 5);
    if (node >= n) return;

    const uint2 qp = Q2[(size_t)node * 32 + l32];
    const float qx = bflo(qp.x), qy = bfhi(qp.x), qz = bflo(qp.y), qw = bfhi(qp.y);

    float dsum = 0.f, a0 = 0.f, a1 = 0.f, a2 = 0.f, a3 = 0.f;
    const int beg = offs[node], end = offs[node + 1];
    const int srcbase = tid & 32;            // this half's lane-0 within the wave

#define EDGE_STEP(kp, vp)                                                      \
    {                                                                          \
        float part = qx * bflo((kp).x) + qy * bfhi((kp).x)                     \
                   + qz * bflo((kp).y) + qw * bfhi((kp).y);                    \
        part += __shfl_xor(part, 1, 64);                                       \
        part += __shfl_xor(part, 2, 64);                                       \
        float w = __expf(part * 0.25f);                                        \
        dsum += w;                                                             \
        a0 += w * bflo((vp).x); a1 += w * bfhi((vp).x);                        \
        a2 += w * bflo((vp).y); a3 += w * bfhi((vp).y);                        \
    }

    for (int base = beg; base < end; base += 32) {
        int cnt = min(32, end - base);
        int my = (base + l32 < end) ? srcl[base + l32] : 0;
        int j = 0;
        for (; j + 2 <= cnt; j += 2) {
            int s0 = __shfl(my, srcbase + j,     64);
            int s1 = __shfl(my, srcbase + j + 1, 64);
            uint2 k0 = K2[(size_t)s0 * 32 + l32];
            uint2 v0 = V2[(size_t)s0 * 32 + l32];
            uint2 k1 = K2[(size_t)s1 * 32 + l32];
            uint2 v1 = V2[(size_t)s1 * 32 + l32];
            EDGE_STEP(k0, v0); EDGE_STEP(k1, v1);
        }
        for (; j < cnt; ++j) {
            int s = __shfl(my, srcbase + j, 64);
            uint2 kk = K2[(size_t)s * 32 + l32];
            uint2 vv = V2[(size_t)s * 32 + l32];
            EDGE_STEP(kk, vv);
        }
    }
#undef EDGE_STEP

    float inv = 1.f / dsum;                  // deg>=1 (identity edges present)
    float4 r = make_float4(a0 * inv, a1 * inv, a2 * inv, a3 * inv);
    *(float4*)&out[(size_t)node * HDIM + l32 * 4] = r;
}

// ---------------------------------------------------------------------------
extern "C" void kernel_launch(void* const* d_in, const int* in_sizes, int n_in,
                              void* d_out, int out_size, void* d_ws, size_t ws_size,
                              hipStream_t stream) {
    const float* q  = (const float*)d_in[0];
    const float* k  = (const float*)d_in[1];
    const float* v  = (const float*)d_in[2];
    const float* Wq = (const float*)d_in[3];
    const float* bq = (const float*)d_in[4];
    const float* Wk = (const float*)d_in[5];
    const float* bk = (const float*)d_in[6];
    const float* Wv = (const float*)d_in[7];
    const float* bv = (const float*)d_in[8];
    const int* qidx = (const int*)d_in[9];
    const int* kidx = (const int*)d_in[10];
    float* out = (float*)d_out;

    const int N = in_sizes[0] / HDIM;
    const int E = in_sizes[9];

    char* p = (char*)d_ws;
    unsigned short* Qb = (unsigned short*)p; p += (size_t)N * HDIM * sizeof(unsigned short);
    unsigned short* Kb = (unsigned short*)p; p += (size_t)N * HDIM * sizeof(unsigned short);
    unsigned short* Vb = (unsigned short*)p; p += (size_t)N * HDIM * sizeof(unsigned short);
    unsigned short* Wopt = (unsigned short*)p; p += (size_t)3 * HDIM * HDIM * sizeof(unsigned short);
    int* deg  = (int*)p; p += (size_t)N * sizeof(int);
    int* offs = (int*)p; p += (size_t)(N + 1) * sizeof(int);
    int* bsum = (int*)p; p += 64 * sizeof(int);
    int* rank = (int*)p; p += (size_t)E * sizeof(int);
    int* srcl = (int*)p; p += (size_t)E * sizeof(int);

    const int nbx = (N + 63) / 64;           // proj x-blocks
    const int neb = (E + 255) / 256;         // edge blocks
    const int nb  = (N + 1023) / 1024;       // scan blocks
    const int initn = (N > 3 * HDIM * HDIM) ? N : 3 * HDIM * HDIM;

    init_kernel<<<(initn + 255) / 256, 256, 0, stream>>>(deg, N, Wq, Wk, Wv, Wopt);
    {
        dim3 grid((nbx > neb) ? nbx : neb, 4);
        proj_deg<<<grid, 256, 0, stream>>>(q, k, v, Wopt, bq, bk, bv, Qb, Kb, Vb,
                                           qidx, deg, rank, E, N, nbx);
    }
    scan_block<<<nb, 1024, 0, stream>>>(deg, offs, bsum, N);
    scan_addtops<<<nb, 1024, 0, stream>>>(bsum, offs, N, E, nb);
    fill_kernel<<<neb, 256, 0, stream>>>(qidx, kidx, offs, rank, srcl, E);
    agg_kernel<<<(N + 7) / 8, 256, 0, stream>>>((const uint2*)Qb, (const uint2*)Kb,
                                                (const uint2*)Vb, offs, srcl, out, N);
}